// Round 16
// baseline (5510.646 us; speedup 1.0000x reference)
//
#include <hip/hip_runtime.h>
#include <hip/hip_bf16.h>
#include <math.h>

#define Bb 64
#define Tt 512
#define Ii 1024
#define Hh 2048
#define NBLK 64

typedef __attribute__((ext_vector_type(8))) short bf16x8;
typedef __attribute__((ext_vector_type(8))) unsigned short ushort8;
typedef __attribute__((ext_vector_type(4))) float f32x4;

__device__ __forceinline__ unsigned short f2bf(float x) {
    unsigned int u = __float_as_uint(x);
    unsigned int r = u + 0x7fffu + ((u >> 16) & 1u);
    return (unsigned short)(r >> 16);
}

// ---------------------------------------------------------------------------
__global__ __launch_bounds__(256) void cvt_kernel(
    const float* __restrict__ src, unsigned short* __restrict__ dst)
{
    const int i = (blockIdx.x * 256 + threadIdx.x) * 4;
    float4 v = *(const float4*)(src + i);
    ushort4 o;
    o.x = f2bf(v.x); o.y = f2bf(v.y); o.z = f2bf(v.z); o.w = f2bf(v.w);
    *(ushort4*)(dst + i) = o;
}

// h0 [64][2048] fp32 -> h_bf[ph][buf0][32][2048] (ph = b>>5, local r = b&31)
__global__ __launch_bounds__(256) void cvt_h0(
    const float* __restrict__ h0, unsigned short* __restrict__ hb)
{
    const int idx = (blockIdx.x * 256 + threadIdx.x) * 4;
    const int b   = idx >> 11;
    const int col = idx & 2047;
    float4 v = *(const float4*)(h0 + idx);
    ushort4 o;
    o.x = f2bf(v.x); o.y = f2bf(v.y); o.z = f2bf(v.z); o.w = f2bf(v.w);
    const int ph = b >> 5, r = b & 31;
    *(ushort4*)(hb + (size_t)(ph * 64 + r) * Hh + col) = o;
}

// flags: [2 halves][64 cg][4 epi-waves] = 512
__global__ __launch_bounds__(512) void init_flags(unsigned int* flags) {
    flags[threadIdx.x] = 0u;
}

// ---------------------------------------------------------------------------
// xproj: out[M=B*T][N=H] = input[M][K=I] @ w_ih^T + b_ih   (bf16 MFMA)
// ---------------------------------------------------------------------------
__global__ __launch_bounds__(256, 2) void xproj_kernel(
    const float* __restrict__ A,
    const unsigned short* __restrict__ Wbf,
    const float* __restrict__ bias,
    float* __restrict__ out)
{
    __shared__ unsigned short As[128 * 40];
    __shared__ unsigned short Bs[128 * 40];

    const int tid  = threadIdx.x;
    const int lane = tid & 63;
    const int wid  = tid >> 6;
    const int wm   = wid & 1;
    const int wn   = wid >> 1;
    const int rlo  = lane & 15;
    const int khi  = lane >> 4;

    const int m0 = blockIdx.y * 128;
    const int n0 = blockIdx.x * 128;

    f32x4 acc[4][4];
    #pragma unroll
    for (int i = 0; i < 4; ++i)
        #pragma unroll
        for (int j = 0; j < 4; ++j) acc[i][j] = (f32x4)0.f;

    for (int k0 = 0; k0 < Ii; k0 += 32) {
        #pragma unroll
        for (int p = 0; p < 4; ++p) {
            const int flat = p * 256 + tid;
            const int row  = flat >> 3;
            const int c4   = flat & 7;
            float4 v = *(const float4*)(A + (size_t)(m0 + row) * Ii + k0 + c4 * 4);
            ushort4 o;
            o.x = f2bf(v.x); o.y = f2bf(v.y); o.z = f2bf(v.z); o.w = f2bf(v.w);
            *(ushort4*)(As + row * 40 + c4 * 4) = o;
        }
        #pragma unroll
        for (int p = 0; p < 2; ++p) {
            const int flat = p * 256 + tid;
            const int row  = flat >> 2;
            const int c8   = flat & 3;
            ushort8 v = *(const ushort8*)(Wbf + (size_t)(n0 + row) * Ii + k0 + c8 * 8);
            *(ushort8*)(Bs + row * 40 + c8 * 8) = v;
        }
        __syncthreads();

        bf16x8 af[4], bfr[4];
        #pragma unroll
        for (int i = 0; i < 4; ++i)
            af[i] = *(const bf16x8*)(As + (wm * 64 + i * 16 + rlo) * 40 + khi * 8);
        #pragma unroll
        for (int j = 0; j < 4; ++j)
            bfr[j] = *(const bf16x8*)(Bs + (wn * 64 + j * 16 + rlo) * 40 + khi * 8);
        #pragma unroll
        for (int i = 0; i < 4; ++i)
            #pragma unroll
            for (int j = 0; j < 4; ++j)
                acc[i][j] = __builtin_amdgcn_mfma_f32_16x16x32_bf16(
                    af[i], bfr[j], acc[i][j], 0, 0, 0);
        __syncthreads();
    }

    #pragma unroll
    for (int j = 0; j < 4; ++j) {
        const int col = n0 + wn * 64 + j * 16 + rlo;
        const float bj = bias[col];
        #pragma unroll
        for (int i = 0; i < 4; ++i) {
            #pragma unroll
            for (int r = 0; r < 4; ++r) {
                const int m = m0 + wm * 64 + i * 16 + khi * 4 + r;
                out[(size_t)m * Hh + col] = acc[i][j][r] + bj;
            }
        }
    }
}

// ---------------------------------------------------------------------------
// asm helpers
// ---------------------------------------------------------------------------
#define LD_FRAG(dst, base, OFF)                                               \
    asm volatile("global_load_dwordx4 %0, %1, off offset:" OFF " sc0 sc1"     \
                 : "=v"(dst) : "v"(base))

#define LD_FRAG_C(dst, base, OFF)                                             \
    asm volatile("global_load_dwordx4 %0, %1, off offset:" OFF                \
                 : "=v"(dst) : "v"(base))

#define DRAIN16(a)                                                            \
    asm volatile("s_waitcnt vmcnt(0)"                                         \
                 : "+v"(a[0][0]), "+v"(a[0][1]), "+v"(a[0][2]), "+v"(a[0][3]),\
                   "+v"(a[0][4]), "+v"(a[0][5]), "+v"(a[0][6]), "+v"(a[0][7]),\
                   "+v"(a[1][0]), "+v"(a[1][1]), "+v"(a[1][2]), "+v"(a[1][3]),\
                   "+v"(a[1][4]), "+v"(a[1][5]), "+v"(a[1][6]), "+v"(a[1][7]) \
                 :: "memory");                                                \
    __builtin_amdgcn_sched_barrier(0)

// Raw barrier: LDS-safe (lgkm drained) but does NOT drain vmcnt.
#define RAW_BARRIER()                                                         \
    asm volatile("s_waitcnt lgkmcnt(0)\n\ts_barrier" ::: "memory")

// ---------------------------------------------------------------------------
// Persistent recurrence, PHASE-INTERLEAVED: 64 WGs x 512 thr (8 waves).
// WG owns cols cg*32..+31 for BOTH row-halves. Per t: phase ph=0 computes
// rows 0..31, phase ph=1 rows 32..63. A half's flags are published one full
// phase before peers consume them -> L3 handoff latency hidden under the
// other half's compute. Per-phase pipeline identical to r15 (verified):
// 16-frag sc0sc1 loads + one DRAIN16, 32 MFMA, ph-buffered LDS reduce + one
// RAW_BARRIER, epilogue on waves 0-3, per-wave h-store drain + flag.
// Depth-2 h ping-pong per half; r15 safety argument applies per half.
// ---------------------------------------------------------------------------
__global__ __launch_bounds__(512, 2) void rnn_persistent(
    const unsigned short* __restrict__ w_bf,   // [2048][2048] bf16
    unsigned short* __restrict__ h_bf,         // [2 ph][2 buf][32][2048] bf16
    const float* __restrict__ b_hh,            // [2048]
    const float* __restrict__ internal,        // [64][512]
    float* __restrict__ out,                   // [B][T][H] ++ [B][H]
    unsigned int* __restrict__ flags)          // [2][64][4]
{
    __shared__ f32x4 red4[2][8 * 256];         // 64 KiB, buffered by phase

    const int tid  = threadIdx.x;
    const int lane = tid & 63;
    const int wid  = tid >> 6;                 // K-slice 0..7
    const int rlo  = lane & 15;
    const int khi  = lane >> 4;
    const int cg   = blockIdx.x;               // cols cg*32..+31

    // ---- preload w_hh slice (register/AGPR-resident across all steps)
    bf16x8 wf[2][8];
    {
        const unsigned short* w0 =
            w_bf + (size_t)(cg * 32 + rlo) * Hh + wid * 256 + khi * 8;
        const unsigned short* w1 = w0 + (size_t)16 * Hh;
        LD_FRAG_C(wf[0][0], w0, "0");   LD_FRAG_C(wf[0][1], w0, "64");
        LD_FRAG_C(wf[0][2], w0, "128"); LD_FRAG_C(wf[0][3], w0, "192");
        LD_FRAG_C(wf[0][4], w0, "256"); LD_FRAG_C(wf[0][5], w0, "320");
        LD_FRAG_C(wf[0][6], w0, "384"); LD_FRAG_C(wf[0][7], w0, "448");
        LD_FRAG_C(wf[1][0], w1, "0");   LD_FRAG_C(wf[1][1], w1, "64");
        LD_FRAG_C(wf[1][2], w1, "128"); LD_FRAG_C(wf[1][3], w1, "192");
        LD_FRAG_C(wf[1][4], w1, "256"); LD_FRAG_C(wf[1][5], w1, "320");
        LD_FRAG_C(wf[1][6], w1, "384"); LD_FRAG_C(wf[1][7], w1, "448");
        DRAIN16(wf);
    }

    // ---- epilogue decode (r9-r15 verified); rAl is LOCAL row 0..31
    const int em    = (tid >> 6) & 1;
    const int ent   = (tid >> 7) & 1;          // valid for tid<256
    const int odd   = lane & 1;
    const int clloc = (ent * 16 + rlo) & ~1;
    const int cl    = cg * 32 + clloc;         // even col of the pair
    const int rAl   = em * 16 + khi * 4 + 2 * odd;   // local row A
    const float2 bh2 = (tid < 256) ? *(const float2*)(b_hh + cl)
                                   : make_float2(0.f, 0.f);

    float2 xpA[2], xpB[2], gAd[2], gBd[2];
    float  nzA[2], nzB[2];
    #pragma unroll
    for (int ph = 0; ph < 2; ++ph) {
        xpA[ph] = make_float2(0.f, 0.f); xpB[ph] = make_float2(0.f, 0.f);
        gAd[ph] = make_float2(0.f, 0.f); gBd[ph] = make_float2(0.f, 0.f);
        nzA[ph] = 0.f; nzB[ph] = 0.f;
    }
    if (tid < 256) {
        #pragma unroll
        for (int ph = 0; ph < 2; ++ph) {
            const int rA = ph * 32 + rAl, rB = rA + 1;
            xpA[ph] = *(const float2*)(out + ((size_t)rA * Tt + 0) * Hh + cl);
            xpB[ph] = *(const float2*)(out + ((size_t)rB * Tt + 0) * Hh + cl);
            nzA[ph] = internal[rA * Tt + 0];
            nzB[ph] = internal[rB * Tt + 0];
        }
    }

    for (int t = 0; t < Tt; ++t) {
        const bool last = (t == Tt - 1);
        #pragma unroll
        for (int ph = 0; ph < 2; ++ph) {
            const unsigned short* h_cur =
                h_bf + (size_t)(ph * 64 + (t & 1) * 32) * Hh;
            unsigned short* h_nxt =
                h_bf + (size_t)(ph * 64 + ((t + 1) & 1) * 32) * Hh;

            // ---- poll this half's producers (published one phase ago)
            if (t) {
                const unsigned int tgt = (unsigned int)t;
                const unsigned int* pf =
                    flags + ph * 256 + wid * 32 + (lane & 31);
                while (true) {
                    unsigned int f = __hip_atomic_load(
                        pf, __ATOMIC_RELAXED, __HIP_MEMORY_SCOPE_AGENT);
                    if (__all(f >= tgt)) break;
                    __builtin_amdgcn_s_sleep(1);
                }
            }

            // ---- issue h loads (16 frags, one drain)
            const unsigned short* am0 =
                h_cur + (size_t)rlo * Hh + wid * 256 + khi * 8;
            const unsigned short* am1 = am0 + (size_t)16 * Hh;

            bf16x8 a[2][8];
            LD_FRAG(a[0][0], am0, "0");   LD_FRAG(a[0][1], am0, "64");
            LD_FRAG(a[0][2], am0, "128"); LD_FRAG(a[0][3], am0, "192");
            LD_FRAG(a[0][4], am0, "256"); LD_FRAG(a[0][5], am0, "320");
            LD_FRAG(a[0][6], am0, "384"); LD_FRAG(a[0][7], am0, "448");
            LD_FRAG(a[1][0], am1, "0");   LD_FRAG(a[1][1], am1, "64");
            LD_FRAG(a[1][2], am1, "128"); LD_FRAG(a[1][3], am1, "192");
            LD_FRAG(a[1][4], am1, "256"); LD_FRAG(a[1][5], am1, "320");
            LD_FRAG(a[1][6], am1, "384"); LD_FRAG(a[1][7], am1, "448");

            // ---- deferred out[t-1] stores ride the same drain
            if (tid < 256 && t > 0) {
                const int rA = ph * 32 + rAl, rB = rA + 1;
                *(float2*)(out + ((size_t)rA * Tt + (t - 1)) * Hh + cl) = gAd[ph];
                *(float2*)(out + ((size_t)rB * Tt + (t - 1)) * Hh + cl) = gBd[ph];
            }

            DRAIN16(a);

            // ---- MFMA: 2 mtiles x 2 ntiles x 8 kits
            f32x4 acc[2][2];
            #pragma unroll
            for (int m = 0; m < 2; ++m)
                #pragma unroll
                for (int nt = 0; nt < 2; ++nt) acc[m][nt] = (f32x4)0.f;
            #pragma unroll
            for (int kk = 0; kk < 8; ++kk)
                #pragma unroll
                for (int m = 0; m < 2; ++m)
                    #pragma unroll
                    for (int nt = 0; nt < 2; ++nt)
                        acc[m][nt] = __builtin_amdgcn_mfma_f32_16x16x32_bf16(
                            a[m][kk], wf[nt][kk], acc[m][nt], 0, 0, 0);

            // ---- k-split reduce, phase-buffered; ONE barrier per phase
            f32x4* rb = red4[ph];
            #pragma unroll
            for (int nt = 0; nt < 2; ++nt)
                #pragma unroll
                for (int m = 0; m < 2; ++m)
                    rb[wid * 256 + (nt * 2 + m) * 64 + lane] = acc[m][nt];
            RAW_BARRIER();

            // ---- epilogue: waves 0-3; waves 4-7 run ahead to next phase
            if (tid < 256) {
                f32x4 s4 = (f32x4)0.f;
                #pragma unroll
                for (int ks = 0; ks < 8; ++ks)
                    s4 += rb[ks * 256 + tid];

                f32x4 o4;
                #pragma unroll
                for (int i = 0; i < 4; ++i)
                    o4[i] = __shfl_xor(s4[i], 1, 64);

                const float sA_lo = odd ? o4[2] : s4[0];
                const float sA_hi = odd ? s4[2] : o4[0];
                const float sB_lo = odd ? o4[3] : s4[1];
                const float sB_hi = odd ? s4[3] : o4[1];

                float2 gA, gB;
                gA.x = tanhf(xpA[ph].x + nzA[ph] + bh2.x + sA_lo);
                gA.y = tanhf(xpA[ph].y + nzA[ph] + bh2.y + sA_hi);
                gB.x = tanhf(xpB[ph].x + nzB[ph] + bh2.x + sB_lo);
                gB.y = tanhf(xpB[ph].y + nzB[ph] + bh2.y + sB_hi);

                const int rA = ph * 32 + rAl, rB = rA + 1;
                const unsigned int hpA =
                    (unsigned int)f2bf(gA.x) | ((unsigned int)f2bf(gA.y) << 16);
                const unsigned int hpB =
                    (unsigned int)f2bf(gB.x) | ((unsigned int)f2bf(gB.y) << 16);
                __hip_atomic_store(
                    (unsigned int*)h_nxt + ((size_t)rAl * Hh + cl) / 2,
                    hpA, __ATOMIC_RELAXED, __HIP_MEMORY_SCOPE_AGENT);
                __hip_atomic_store(
                    (unsigned int*)h_nxt + ((size_t)(rAl + 1) * Hh + cl) / 2,
                    hpB, __ATOMIC_RELAXED, __HIP_MEMORY_SCOPE_AGENT);

                if (last) {
                    *(float2*)(out + ((size_t)rA * Tt + t) * Hh + cl) = gA;
                    *(float2*)(out + ((size_t)rB * Tt + t) * Hh + cl) = gB;
                    float* tail = out + (size_t)Bb * Tt * Hh;
                    *(float2*)(tail + (size_t)rA * Hh + cl) = gA;
                    *(float2*)(tail + (size_t)rB * Hh + cl) = gB;
                } else {
                    gAd[ph] = gA; gBd[ph] = gB;

                    // per-WAVE drain of own h stores, then own flag
                    asm volatile("s_waitcnt vmcnt(0)" ::: "memory");
                    if (lane == 0)
                        __hip_atomic_store(flags + ph * 256 + cg * 4 + wid,
                                           (unsigned int)(t + 1),
                                           __ATOMIC_RELAXED,
                                           __HIP_MEMORY_SCOPE_AGENT);

                    // xp/nz prefetch for (t+1, ph): a full round to arrive
                    xpA[ph] = *(const float2*)(out + ((size_t)rA * Tt + t + 1) * Hh + cl);
                    xpB[ph] = *(const float2*)(out + ((size_t)rB * Tt + t + 1) * Hh + cl);
                    nzA[ph] = internal[rA * Tt + t + 1];
                    nzB[ph] = internal[rB * Tt + t + 1];
                }
            }
        }
    }
}

// ---------------------------------------------------------------------------
extern "C" void kernel_launch(void* const* d_in, const int* in_sizes, int n_in,
                              void* d_out, int out_size, void* d_ws, size_t ws_size,
                              hipStream_t stream) {
    const float* input    = (const float*)d_in[0];
    const float* internal = (const float*)d_in[1];
    const float* w_ih     = (const float*)d_in[2];
    const float* w_hh     = (const float*)d_in[3];
    const float* b_ih     = (const float*)d_in[4];
    const float* b_hh     = (const float*)d_in[5];
    const float* h0       = (const float*)d_in[6];
    float* out = (float*)d_out;

    // ws: w_hh_bf [4M us] | w_ih_bf [2M us] | h_bf[2][2][32][2048] | flags[512]
    unsigned short* w_hh_bf = (unsigned short*)d_ws;
    unsigned short* w_ih_bf = w_hh_bf + (size_t)Hh * Hh;
    unsigned short* h_bf    = w_ih_bf + (size_t)Hh * Ii;
    unsigned int*   flags   = (unsigned int*)(h_bf + (size_t)2 * Bb * Hh);

    hipLaunchKernelGGL(init_flags, dim3(1), dim3(512), 0, stream, flags);
    hipLaunchKernelGGL(cvt_kernel, dim3((Hh * Hh) / 1024), dim3(256), 0, stream,
                       w_hh, w_hh_bf);
    hipLaunchKernelGGL(cvt_kernel, dim3((Hh * Ii) / 1024), dim3(256), 0, stream,
                       w_ih, w_ih_bf);
    hipLaunchKernelGGL(cvt_h0, dim3((Bb * Hh) / 1024), dim3(256), 0, stream,
                       h0, h_bf);

    dim3 g1(Hh / 128, (Bb * Tt) / 128);
    hipLaunchKernelGGL(xproj_kernel, g1, dim3(256), 0, stream,
                       input, w_ih_bf, b_ih, out);

    void* args[] = {(void*)&w_hh_bf, (void*)&h_bf, (void*)&b_hh,
                    (void*)&internal, (void*)&out, (void*)&flags};
    hipLaunchCooperativeKernel((void*)rnn_persistent, dim3(NBLK), dim3(512),
                               args, 0, stream);
}

// Round 17
// 4556.285 us; speedup vs baseline: 1.2095x; 1.2095x over previous
//
#include <hip/hip_runtime.h>
#include <hip/hip_bf16.h>
#include <math.h>

#define Bb 64
#define Tt 512
#define Ii 1024
#define Hh 2048
#define NBLK 128

typedef __attribute__((ext_vector_type(8))) short bf16x8;
typedef __attribute__((ext_vector_type(8))) unsigned short ushort8;
typedef __attribute__((ext_vector_type(4))) float f32x4;

__device__ __forceinline__ unsigned short f2bf(float x) {
    unsigned int u = __float_as_uint(x);
    unsigned int r = u + 0x7fffu + ((u >> 16) & 1u);
    return (unsigned short)(r >> 16);
}

// ---------------------------------------------------------------------------
__global__ __launch_bounds__(256) void cvt_kernel(
    const float* __restrict__ src, unsigned short* __restrict__ dst)
{
    const size_t i = ((size_t)blockIdx.x * 256 + threadIdx.x) * 4;
    float4 v = *(const float4*)(src + i);
    ushort4 o;
    o.x = f2bf(v.x); o.y = f2bf(v.y); o.z = f2bf(v.z); o.w = f2bf(v.w);
    *(ushort4*)(dst + i) = o;
}

// flags: [512] per-epi-wave arrivals | [512] replicated roots
__global__ __launch_bounds__(1024) void init_flags(unsigned int* flags) {
    flags[threadIdx.x] = 0u;
}

// ---------------------------------------------------------------------------
// xproj (fallback path only)
// ---------------------------------------------------------------------------
__global__ __launch_bounds__(256, 2) void xproj_kernel(
    const float* __restrict__ A,
    const unsigned short* __restrict__ Wbf,
    const float* __restrict__ bias,
    float* __restrict__ out)
{
    __shared__ unsigned short As[128 * 40];
    __shared__ unsigned short Bs[128 * 40];

    const int tid  = threadIdx.x;
    const int lane = tid & 63;
    const int wid  = tid >> 6;
    const int wm   = wid & 1;
    const int wn   = wid >> 1;
    const int rlo  = lane & 15;
    const int khi  = lane >> 4;

    const int m0 = blockIdx.y * 128;
    const int n0 = blockIdx.x * 128;

    f32x4 acc[4][4];
    #pragma unroll
    for (int i = 0; i < 4; ++i)
        #pragma unroll
        for (int j = 0; j < 4; ++j) acc[i][j] = (f32x4)0.f;

    for (int k0 = 0; k0 < Ii; k0 += 32) {
        #pragma unroll
        for (int p = 0; p < 4; ++p) {
            const int flat = p * 256 + tid;
            const int row  = flat >> 3;
            const int c4   = flat & 7;
            float4 v = *(const float4*)(A + (size_t)(m0 + row) * Ii + k0 + c4 * 4);
            ushort4 o;
            o.x = f2bf(v.x); o.y = f2bf(v.y); o.z = f2bf(v.z); o.w = f2bf(v.w);
            *(ushort4*)(As + row * 40 + c4 * 4) = o;
        }
        #pragma unroll
        for (int p = 0; p < 2; ++p) {
            const int flat = p * 256 + tid;
            const int row  = flat >> 2;
            const int c8   = flat & 3;
            ushort8 v = *(const ushort8*)(Wbf + (size_t)(n0 + row) * Ii + k0 + c8 * 8);
            *(ushort8*)(Bs + row * 40 + c8 * 8) = v;
        }
        __syncthreads();

        bf16x8 af[4], bfr[4];
        #pragma unroll
        for (int i = 0; i < 4; ++i)
            af[i] = *(const bf16x8*)(As + (wm * 64 + i * 16 + rlo) * 40 + khi * 8);
        #pragma unroll
        for (int j = 0; j < 4; ++j)
            bfr[j] = *(const bf16x8*)(Bs + (wn * 64 + j * 16 + rlo) * 40 + khi * 8);
        #pragma unroll
        for (int i = 0; i < 4; ++i)
            #pragma unroll
            for (int j = 0; j < 4; ++j)
                acc[i][j] = __builtin_amdgcn_mfma_f32_16x16x32_bf16(
                    af[i], bfr[j], acc[i][j], 0, 0, 0);
        __syncthreads();
    }

    #pragma unroll
    for (int j = 0; j < 4; ++j) {
        const int col = n0 + wn * 64 + j * 16 + rlo;
        const float bj = bias[col];
        #pragma unroll
        for (int i = 0; i < 4; ++i) {
            #pragma unroll
            for (int r = 0; r < 4; ++r) {
                const int m = m0 + wm * 64 + i * 16 + khi * 4 + r;
                out[(size_t)m * Hh + col] = acc[i][j][r] + bj;
            }
        }
    }
}

// ---------------------------------------------------------------------------
// asm helpers
// ---------------------------------------------------------------------------
#define LD_FRAG(dst, base, OFF)                                               \
    asm volatile("global_load_dwordx4 %0, %1, off offset:" OFF " sc0 sc1"     \
                 : "=v"(dst) : "v"(base))

#define LD_FRAG_C(dst, base, OFF)                                             \
    asm volatile("global_load_dwordx4 %0, %1, off offset:" OFF                \
                 : "=v"(dst) : "v"(base))

#define DRAIN16(a)                                                            \
    asm volatile("s_waitcnt vmcnt(0)"                                         \
                 : "+v"(a[0][0]), "+v"(a[0][1]), "+v"(a[0][2]), "+v"(a[0][3]),\
                   "+v"(a[0][4]), "+v"(a[0][5]), "+v"(a[0][6]), "+v"(a[0][7]),\
                   "+v"(a[1][0]), "+v"(a[1][1]), "+v"(a[1][2]), "+v"(a[1][3]),\
                   "+v"(a[1][4]), "+v"(a[1][5]), "+v"(a[1][6]), "+v"(a[1][7]) \
                 :: "memory");                                                \
    __builtin_amdgcn_sched_barrier(0)

#define DRAIN8(x)                                                             \
    asm volatile("s_waitcnt vmcnt(0)"                                         \
                 : "+v"(x[0][0]), "+v"(x[0][1]), "+v"(x[0][2]), "+v"(x[0][3]),\
                   "+v"(x[1][0]), "+v"(x[1][1]), "+v"(x[1][2]), "+v"(x[1][3]) \
                 :: "memory");                                                \
    __builtin_amdgcn_sched_barrier(0)

#define RAW_BARRIER()                                                         \
    asm volatile("s_waitcnt lgkmcnt(0)\n\ts_barrier" ::: "memory")

// ===========================================================================
// FUSED persistent recurrence (r14 skeleton + in-bubble x_proj GEMM).
// 128 WGs x 512 thr. WG = (rh, cg). Wave wid = K-slice of H (256) and of
// I (128). w_hh & w_ih slices register(AGPR)-resident. Per step:
//   h loads + next-step input loads ride ONE drain; h-MFMA accumulates on
//   top of acc_x (x-contribution computed LAST step in the bubble);
//   one LDS reduce covers x+h; epilogue tanh(s4+nz+b_ih+b_hh) -> out + h.
// Sync = r14's verified tree (per-epi-wave flags -> aggregator -> x16
// replicated roots).
// ===========================================================================
__global__ __launch_bounds__(512, 2) void rnn_persistent_fused(
    const unsigned short* __restrict__ w_bf,   // w_hh bf16 [2048][2048]
    const unsigned short* __restrict__ wx_bf,  // w_ih bf16 [2048][1024]
    const unsigned short* __restrict__ x_bf,   // input bf16 [64][512][1024]
    unsigned short* __restrict__ h_bf,         // [2][64][2048] ping-pong
    const float* __restrict__ b_ih,            // [2048]
    const float* __restrict__ b_hh,            // [2048]
    const float* __restrict__ internal,        // [64][512]
    float* __restrict__ out,                   // [B][T][H] ++ [B][H]
    unsigned int* __restrict__ flags)          // [512]+[512]
{
    __shared__ f32x4 red4[8 * 256];

    const int tid  = threadIdx.x;
    const int lane = tid & 63;
    const int wid  = tid >> 6;
    const int rlo  = lane & 15;
    const int khi  = lane >> 4;
    const int blk  = blockIdx.x;
    const int rh   = blk & 1;
    const int cg   = blk >> 1;

    // ---- preload w_hh slice (16 frags)
    bf16x8 wf[2][8];
    {
        const unsigned short* w0 =
            w_bf + (size_t)(cg * 32 + rlo) * Hh + wid * 256 + khi * 8;
        const unsigned short* w1 = w0 + (size_t)16 * Hh;
        LD_FRAG_C(wf[0][0], w0, "0");   LD_FRAG_C(wf[0][1], w0, "64");
        LD_FRAG_C(wf[0][2], w0, "128"); LD_FRAG_C(wf[0][3], w0, "192");
        LD_FRAG_C(wf[0][4], w0, "256"); LD_FRAG_C(wf[0][5], w0, "320");
        LD_FRAG_C(wf[0][6], w0, "384"); LD_FRAG_C(wf[0][7], w0, "448");
        LD_FRAG_C(wf[1][0], w1, "0");   LD_FRAG_C(wf[1][1], w1, "64");
        LD_FRAG_C(wf[1][2], w1, "128"); LD_FRAG_C(wf[1][3], w1, "192");
        LD_FRAG_C(wf[1][4], w1, "256"); LD_FRAG_C(wf[1][5], w1, "320");
        LD_FRAG_C(wf[1][6], w1, "384"); LD_FRAG_C(wf[1][7], w1, "448");
        DRAIN16(wf);
    }
    // ---- preload w_ih slice (8 frags; K-slice wid*128)
    bf16x8 wxr[2][4];
    {
        const unsigned short* q0 =
            wx_bf + (size_t)(cg * 32 + rlo) * Ii + wid * 128 + khi * 8;
        const unsigned short* q1 = q0 + (size_t)16 * Ii;
        LD_FRAG_C(wxr[0][0], q0, "0");   LD_FRAG_C(wxr[0][1], q0, "64");
        LD_FRAG_C(wxr[0][2], q0, "128"); LD_FRAG_C(wxr[0][3], q0, "192");
        LD_FRAG_C(wxr[1][0], q1, "0");   LD_FRAG_C(wxr[1][1], q1, "64");
        LD_FRAG_C(wxr[1][2], q1, "128"); LD_FRAG_C(wxr[1][3], q1, "192");
        DRAIN8(wxr);
    }

    // ---- epilogue decode (r9-r14 verified)
    const int em    = (tid >> 6) & 1;
    const int ent   = (tid >> 7) & 1;
    const int odd   = lane & 1;
    const int clloc = (ent * 16 + rlo) & ~1;
    const int cl    = cg * 32 + clloc;
    const int rAl   = em * 16 + khi * 4 + 2 * odd;
    const int rAg   = rh * 32 + rAl;
    const int rBg   = rAg + 1;
    float2 bh2 = make_float2(0.f, 0.f);
    float  nzA = 0.f, nzB = 0.f;
    if (tid < 256) {
        const float2 bi = *(const float2*)(b_ih + cl);
        const float2 bh = *(const float2*)(b_hh + cl);
        bh2 = make_float2(bi.x + bh.x, bi.y + bh.y);
        nzA = internal[rAg * Tt + 0];
        nzB = internal[rBg * Tt + 0];
    }
    float2 gA_d = make_float2(0.f, 0.f), gB_d = make_float2(0.f, 0.f);

    // sync addresses (r14)
    unsigned int* myflag   = flags + blk * 4 + wid;
    unsigned int* aggbase  = flags + 8 * lane + 4 * rh;
    unsigned int* rootst   = flags + 512 + (rh * 16 + lane) * 16;
    unsigned int* rootpoll = flags + 512 + (rh * 16 + ((blk >> 1) & 15)) * 16;

    // ---- x row pointers + prologue x-GEMM for t = 0
    const unsigned short* xm0 =
        x_bf + (size_t)(rh * 32 + rlo) * (Tt * Ii) + wid * 128 + khi * 8;
    const unsigned short* xm1 = xm0 + (size_t)16 * (Tt * Ii);

    f32x4 acc_x[2][2];
    {
        bf16x8 xa[2][4];
        LD_FRAG_C(xa[0][0], xm0, "0");   LD_FRAG_C(xa[0][1], xm0, "64");
        LD_FRAG_C(xa[0][2], xm0, "128"); LD_FRAG_C(xa[0][3], xm0, "192");
        LD_FRAG_C(xa[1][0], xm1, "0");   LD_FRAG_C(xa[1][1], xm1, "64");
        LD_FRAG_C(xa[1][2], xm1, "128"); LD_FRAG_C(xa[1][3], xm1, "192");
        DRAIN8(xa);
        #pragma unroll
        for (int m = 0; m < 2; ++m)
            #pragma unroll
            for (int nt = 0; nt < 2; ++nt) acc_x[m][nt] = (f32x4)0.f;
        #pragma unroll
        for (int kk = 0; kk < 4; ++kk)
            #pragma unroll
            for (int m = 0; m < 2; ++m)
                #pragma unroll
                for (int nt = 0; nt < 2; ++nt)
                    acc_x[m][nt] = __builtin_amdgcn_mfma_f32_16x16x32_bf16(
                        xa[m][kk], wxr[nt][kk], acc_x[m][nt], 0, 0, 0);
        xm0 += Ii; xm1 += Ii;
    }

    for (int t = 0; t < Tt; ++t) {
        const bool last = (t == Tt - 1);
        const unsigned short* h_cur = h_bf + (size_t)(t & 1) * Bb * Hh;
        unsigned short*       h_nxt = h_bf + (size_t)((t + 1) & 1) * Bb * Hh;

        // ---- (a) h loads
        const unsigned short* am0 =
            h_cur + (size_t)(rh * 32 + rlo) * Hh + wid * 256 + khi * 8;
        const unsigned short* am1 = am0 + (size_t)16 * Hh;

        bf16x8 a[2][8];
        LD_FRAG(a[0][0], am0, "0");   LD_FRAG(a[0][1], am0, "64");
        LD_FRAG(a[0][2], am0, "128"); LD_FRAG(a[0][3], am0, "192");
        LD_FRAG(a[0][4], am0, "256"); LD_FRAG(a[0][5], am0, "320");
        LD_FRAG(a[0][6], am0, "384"); LD_FRAG(a[0][7], am0, "448");
        LD_FRAG(a[1][0], am1, "0");   LD_FRAG(a[1][1], am1, "64");
        LD_FRAG(a[1][2], am1, "128"); LD_FRAG(a[1][3], am1, "192");
        LD_FRAG(a[1][4], am1, "256"); LD_FRAG(a[1][5], am1, "320");
        LD_FRAG(a[1][6], am1, "384"); LD_FRAG(a[1][7], am1, "448");

        // ---- (a2) input loads for step t+1 (cached; ride same drain)
        bf16x8 xa[2][4];
        if (!last) {
            LD_FRAG_C(xa[0][0], xm0, "0");   LD_FRAG_C(xa[0][1], xm0, "64");
            LD_FRAG_C(xa[0][2], xm0, "128"); LD_FRAG_C(xa[0][3], xm0, "192");
            LD_FRAG_C(xa[1][0], xm1, "0");   LD_FRAG_C(xa[1][1], xm1, "64");
            LD_FRAG_C(xa[1][2], xm1, "128"); LD_FRAG_C(xa[1][3], xm1, "192");
            xm0 += Ii; xm1 += Ii;
        }

        // ---- (b) deferred out[t-1] stores ride the drain
        if (tid < 256 && t > 0) {
            *(float2*)(out + ((size_t)rAg * Tt + (t - 1)) * Hh + cl) = gA_d;
            *(float2*)(out + ((size_t)rBg * Tt + (t - 1)) * Hh + cl) = gB_d;
        }

        // ---- (d) drains
        DRAIN16(a);
        if (!last) { DRAIN8(xa); }

        // ---- (e) h-MFMA, accumulating on top of acc_x (x for step t)
        f32x4 acc[2][2];
        #pragma unroll
        for (int m = 0; m < 2; ++m)
            #pragma unroll
            for (int nt = 0; nt < 2; ++nt) acc[m][nt] = acc_x[m][nt];
        #pragma unroll
        for (int kk = 0; kk < 8; ++kk)
            #pragma unroll
            for (int m = 0; m < 2; ++m)
                #pragma unroll
                for (int nt = 0; nt < 2; ++nt)
                    acc[m][nt] = __builtin_amdgcn_mfma_f32_16x16x32_bf16(
                        a[m][kk], wf[nt][kk], acc[m][nt], 0, 0, 0);

        // ---- (f) k-split reduce (covers x + h)
        #pragma unroll
        for (int nt = 0; nt < 2; ++nt)
            #pragma unroll
            for (int m = 0; m < 2; ++m)
                red4[wid * 256 + (nt * 2 + m) * 64 + lane] = acc[m][nt];
        RAW_BARRIER();

        // ---- (g) epilogue: waves 0-3
        if (tid < 256) {
            f32x4 s4 = (f32x4)0.f;
            #pragma unroll
            for (int ks = 0; ks < 8; ++ks)
                s4 += red4[ks * 256 + tid];

            f32x4 o4;
            #pragma unroll
            for (int i = 0; i < 4; ++i)
                o4[i] = __shfl_xor(s4[i], 1, 64);

            const float sA_lo = odd ? o4[2] : s4[0];
            const float sA_hi = odd ? s4[2] : o4[0];
            const float sB_lo = odd ? o4[3] : s4[1];
            const float sB_hi = odd ? s4[3] : o4[1];

            float2 gA, gB;
            gA.x = tanhf(nzA + bh2.x + sA_lo);
            gA.y = tanhf(nzA + bh2.y + sA_hi);
            gB.x = tanhf(nzB + bh2.x + sB_lo);
            gB.y = tanhf(nzB + bh2.y + sB_hi);

            const unsigned int hpA =
                (unsigned int)f2bf(gA.x) | ((unsigned int)f2bf(gA.y) << 16);
            const unsigned int hpB =
                (unsigned int)f2bf(gB.x) | ((unsigned int)f2bf(gB.y) << 16);
            __hip_atomic_store((unsigned int*)h_nxt + ((size_t)rAg * Hh + cl) / 2,
                               hpA, __ATOMIC_RELAXED, __HIP_MEMORY_SCOPE_AGENT);
            __hip_atomic_store((unsigned int*)h_nxt + ((size_t)rBg * Hh + cl) / 2,
                               hpB, __ATOMIC_RELAXED, __HIP_MEMORY_SCOPE_AGENT);

            if (last) {
                *(float2*)(out + ((size_t)rAg * Tt + t) * Hh + cl) = gA;
                *(float2*)(out + ((size_t)rBg * Tt + t) * Hh + cl) = gB;
                float* tail = out + (size_t)Bb * Tt * Hh;
                *(float2*)(tail + (size_t)rAg * Hh + cl) = gA;
                *(float2*)(tail + (size_t)rBg * Hh + cl) = gB;
            } else {
                gA_d = gA; gB_d = gB;
                asm volatile("s_waitcnt vmcnt(0)" ::: "memory");
                if (lane == 0)
                    __hip_atomic_store(myflag, (unsigned int)(t + 1),
                                       __ATOMIC_RELAXED,
                                       __HIP_MEMORY_SCOPE_AGENT);
                nzA = internal[rAg * Tt + t + 1];
                nzB = internal[rBg * Tt + t + 1];
            }
        }

        // ---- (e2) x-MFMA for step t+1 (fills the sync bubble)
        if (!last) {
            #pragma unroll
            for (int m = 0; m < 2; ++m)
                #pragma unroll
                for (int nt = 0; nt < 2; ++nt) acc_x[m][nt] = (f32x4)0.f;
            #pragma unroll
            for (int kk = 0; kk < 4; ++kk)
                #pragma unroll
                for (int m = 0; m < 2; ++m)
                    #pragma unroll
                    for (int nt = 0; nt < 2; ++nt)
                        acc_x[m][nt] = __builtin_amdgcn_mfma_f32_16x16x32_bf16(
                            xa[m][kk], wxr[nt][kk], acc_x[m][nt], 0, 0, 0);
        }
        if (last) break;

        // ---- tree barrier (r14 verified: aggregator + replicated roots)
        const unsigned int tgt = (unsigned int)(t + 1);
        if (blk < 2 && wid == 7) {
            unsigned int f0, f1, f2, f3;
            while (true) {
                asm volatile("global_load_dword %0, %1, off sc0 sc1"
                             : "=v"(f0) : "v"(aggbase));
                asm volatile("global_load_dword %0, %1, off offset:4 sc0 sc1"
                             : "=v"(f1) : "v"(aggbase));
                asm volatile("global_load_dword %0, %1, off offset:8 sc0 sc1"
                             : "=v"(f2) : "v"(aggbase));
                asm volatile("global_load_dword %0, %1, off offset:12 sc0 sc1"
                             : "=v"(f3) : "v"(aggbase));
                asm volatile("s_waitcnt vmcnt(0)"
                             : "+v"(f0), "+v"(f1), "+v"(f2), "+v"(f3)
                             :: "memory");
                if (__all(f0 >= tgt && f1 >= tgt && f2 >= tgt && f3 >= tgt))
                    break;
                __builtin_amdgcn_s_sleep(1);
            }
            if (lane < 16)
                __hip_atomic_store(rootst, tgt, __ATOMIC_RELAXED,
                                   __HIP_MEMORY_SCOPE_AGENT);
        } else if (wid == 7) {
            while (__hip_atomic_load(rootpoll, __ATOMIC_RELAXED,
                                     __HIP_MEMORY_SCOPE_AGENT) < tgt)
                __builtin_amdgcn_s_sleep(1);
        }
        RAW_BARRIER();
    }
}

// ===========================================================================
// FALLBACK persistent recurrence = round-14 kernel verbatim (3808 us PASS).
// ===========================================================================
__global__ __launch_bounds__(512, 2) void rnn_persistent_fb(
    const unsigned short* __restrict__ w_bf,
    unsigned short* __restrict__ h_bf,
    const float* __restrict__ b_hh,
    const float* __restrict__ internal,
    float* __restrict__ out,
    unsigned int* __restrict__ flags)
{
    __shared__ f32x4 red4[8 * 256];

    const int tid  = threadIdx.x;
    const int lane = tid & 63;
    const int wid  = tid >> 6;
    const int rlo  = lane & 15;
    const int khi  = lane >> 4;
    const int blk  = blockIdx.x;
    const int rh   = blk & 1;
    const int cg   = blk >> 1;

    bf16x8 wf[2][8];
    {
        const unsigned short* w0 =
            w_bf + (size_t)(cg * 32 + rlo) * Hh + wid * 256 + khi * 8;
        const unsigned short* w1 = w0 + (size_t)16 * Hh;
        LD_FRAG_C(wf[0][0], w0, "0");   LD_FRAG_C(wf[0][1], w0, "64");
        LD_FRAG_C(wf[0][2], w0, "128"); LD_FRAG_C(wf[0][3], w0, "192");
        LD_FRAG_C(wf[0][4], w0, "256"); LD_FRAG_C(wf[0][5], w0, "320");
        LD_FRAG_C(wf[0][6], w0, "384"); LD_FRAG_C(wf[0][7], w0, "448");
        LD_FRAG_C(wf[1][0], w1, "0");   LD_FRAG_C(wf[1][1], w1, "64");
        LD_FRAG_C(wf[1][2], w1, "128"); LD_FRAG_C(wf[1][3], w1, "192");
        LD_FRAG_C(wf[1][4], w1, "256"); LD_FRAG_C(wf[1][5], w1, "320");
        LD_FRAG_C(wf[1][6], w1, "384"); LD_FRAG_C(wf[1][7], w1, "448");
        DRAIN16(wf);
    }

    const int em    = (tid >> 6) & 1;
    const int ent   = (tid >> 7) & 1;
    const int odd   = lane & 1;
    const int clloc = (ent * 16 + rlo) & ~1;
    const int cl    = cg * 32 + clloc;
    const int rAl   = em * 16 + khi * 4 + 2 * odd;
    const int rAg   = rh * 32 + rAl;
    const int rBg   = rAg + 1;
    const float2 bh2 = (tid < 256) ? *(const float2*)(b_hh + cl)
                                   : make_float2(0.f, 0.f);

    float2 xpA = make_float2(0.f, 0.f), xpB = make_float2(0.f, 0.f);
    float  nzA = 0.f, nzB = 0.f;
    if (tid < 256) {
        xpA = *(const float2*)(out + ((size_t)rAg * Tt + 0) * Hh + cl);
        xpB = *(const float2*)(out + ((size_t)rBg * Tt + 0) * Hh + cl);
        nzA = internal[rAg * Tt + 0];
        nzB = internal[rBg * Tt + 0];
    }
    float2 gA_d = make_float2(0.f, 0.f), gB_d = make_float2(0.f, 0.f);

    unsigned int* myflag   = flags + blk * 4 + wid;
    unsigned int* aggbase  = flags + 8 * lane + 4 * rh;
    unsigned int* rootst   = flags + 512 + (rh * 16 + lane) * 16;
    unsigned int* rootpoll = flags + 512 + (rh * 16 + ((blk >> 1) & 15)) * 16;

    for (int t = 0; t < Tt; ++t) {
        const bool last = (t == Tt - 1);
        const unsigned short* h_cur = h_bf + (size_t)(t & 1) * Bb * Hh;
        unsigned short*       h_nxt = h_bf + (size_t)((t + 1) & 1) * Bb * Hh;

        const unsigned short* am0 =
            h_cur + (size_t)(rh * 32 + rlo) * Hh + wid * 256 + khi * 8;
        const unsigned short* am1 = am0 + (size_t)16 * Hh;

        bf16x8 a[2][8];
        LD_FRAG(a[0][0], am0, "0");   LD_FRAG(a[0][1], am0, "64");
        LD_FRAG(a[0][2], am0, "128"); LD_FRAG(a[0][3], am0, "192");
        LD_FRAG(a[0][4], am0, "256"); LD_FRAG(a[0][5], am0, "320");
        LD_FRAG(a[0][6], am0, "384"); LD_FRAG(a[0][7], am0, "448");
        LD_FRAG(a[1][0], am1, "0");   LD_FRAG(a[1][1], am1, "64");
        LD_FRAG(a[1][2], am1, "128"); LD_FRAG(a[1][3], am1, "192");
        LD_FRAG(a[1][4], am1, "256"); LD_FRAG(a[1][5], am1, "320");
        LD_FRAG(a[1][6], am1, "384"); LD_FRAG(a[1][7], am1, "448");

        if (tid < 256 && t > 0) {
            *(float2*)(out + ((size_t)rAg * Tt + (t - 1)) * Hh + cl) = gA_d;
            *(float2*)(out + ((size_t)rBg * Tt + (t - 1)) * Hh + cl) = gB_d;
        }

        DRAIN16(a);

        f32x4 acc[2][2];
        #pragma unroll
        for (int m = 0; m < 2; ++m)
            #pragma unroll
            for (int nt = 0; nt < 2; ++nt) acc[m][nt] = (f32x4)0.f;
        #pragma unroll
        for (int kk = 0; kk < 8; ++kk)
            #pragma unroll
            for (int m = 0; m < 2; ++m)
                #pragma unroll
                for (int nt = 0; nt < 2; ++nt)
                    acc[m][nt] = __builtin_amdgcn_mfma_f32_16x16x32_bf16(
                        a[m][kk], wf[nt][kk], acc[m][nt], 0, 0, 0);

        #pragma unroll
        for (int nt = 0; nt < 2; ++nt)
            #pragma unroll
            for (int m = 0; m < 2; ++m)
                red4[wid * 256 + (nt * 2 + m) * 64 + lane] = acc[m][nt];
        RAW_BARRIER();

        if (tid < 256) {
            f32x4 s4 = (f32x4)0.f;
            #pragma unroll
            for (int ks = 0; ks < 8; ++ks)
                s4 += red4[ks * 256 + tid];

            f32x4 o4;
            #pragma unroll
            for (int i = 0; i < 4; ++i)
                o4[i] = __shfl_xor(s4[i], 1, 64);

            const float sA_lo = odd ? o4[2] : s4[0];
            const float sA_hi = odd ? s4[2] : o4[0];
            const float sB_lo = odd ? o4[3] : s4[1];
            const float sB_hi = odd ? s4[3] : o4[1];

            float2 gA, gB;
            gA.x = tanhf(xpA.x + nzA + bh2.x + sA_lo);
            gA.y = tanhf(xpA.y + nzA + bh2.y + sA_hi);
            gB.x = tanhf(xpB.x + nzB + bh2.x + sB_lo);
            gB.y = tanhf(xpB.y + nzB + bh2.y + sB_hi);

            const unsigned int hpA =
                (unsigned int)f2bf(gA.x) | ((unsigned int)f2bf(gA.y) << 16);
            const unsigned int hpB =
                (unsigned int)f2bf(gB.x) | ((unsigned int)f2bf(gB.y) << 16);
            __hip_atomic_store((unsigned int*)h_nxt + ((size_t)rAg * Hh + cl) / 2,
                               hpA, __ATOMIC_RELAXED, __HIP_MEMORY_SCOPE_AGENT);
            __hip_atomic_store((unsigned int*)h_nxt + ((size_t)rBg * Hh + cl) / 2,
                               hpB, __ATOMIC_RELAXED, __HIP_MEMORY_SCOPE_AGENT);

            if (last) {
                *(float2*)(out + ((size_t)rAg * Tt + t) * Hh + cl) = gA;
                *(float2*)(out + ((size_t)rBg * Tt + t) * Hh + cl) = gB;
                float* tail = out + (size_t)Bb * Tt * Hh;
                *(float2*)(tail + (size_t)rAg * Hh + cl) = gA;
                *(float2*)(tail + (size_t)rBg * Hh + cl) = gB;
            } else {
                gA_d = gA; gB_d = gB;
                asm volatile("s_waitcnt vmcnt(0)" ::: "memory");
                if (lane == 0)
                    __hip_atomic_store(myflag, (unsigned int)(t + 1),
                                       __ATOMIC_RELAXED,
                                       __HIP_MEMORY_SCOPE_AGENT);
                xpA = *(const float2*)(out + ((size_t)rAg * Tt + t + 1) * Hh + cl);
                xpB = *(const float2*)(out + ((size_t)rBg * Tt + t + 1) * Hh + cl);
                nzA = internal[rAg * Tt + t + 1];
                nzB = internal[rBg * Tt + t + 1];
            }
        }
        if (last) break;

        const unsigned int tgt = (unsigned int)(t + 1);
        if (blk < 2 && wid == 7) {
            unsigned int f0, f1, f2, f3;
            while (true) {
                asm volatile("global_load_dword %0, %1, off sc0 sc1"
                             : "=v"(f0) : "v"(aggbase));
                asm volatile("global_load_dword %0, %1, off offset:4 sc0 sc1"
                             : "=v"(f1) : "v"(aggbase));
                asm volatile("global_load_dword %0, %1, off offset:8 sc0 sc1"
                             : "=v"(f2) : "v"(aggbase));
                asm volatile("global_load_dword %0, %1, off offset:12 sc0 sc1"
                             : "=v"(f3) : "v"(aggbase));
                asm volatile("s_waitcnt vmcnt(0)"
                             : "+v"(f0), "+v"(f1), "+v"(f2), "+v"(f3)
                             :: "memory");
                if (__all(f0 >= tgt && f1 >= tgt && f2 >= tgt && f3 >= tgt))
                    break;
                __builtin_amdgcn_s_sleep(1);
            }
            if (lane < 16)
                __hip_atomic_store(rootst, tgt, __ATOMIC_RELAXED,
                                   __HIP_MEMORY_SCOPE_AGENT);
        } else if (wid == 7) {
            while (__hip_atomic_load(rootpoll, __ATOMIC_RELAXED,
                                     __HIP_MEMORY_SCOPE_AGENT) < tgt)
                __builtin_amdgcn_s_sleep(1);
        }
        RAW_BARRIER();
    }
}

// ---------------------------------------------------------------------------
extern "C" void kernel_launch(void* const* d_in, const int* in_sizes, int n_in,
                              void* d_out, int out_size, void* d_ws, size_t ws_size,
                              hipStream_t stream) {
    const float* input    = (const float*)d_in[0];
    const float* internal = (const float*)d_in[1];
    const float* w_ih     = (const float*)d_in[2];
    const float* w_hh     = (const float*)d_in[3];
    const float* b_ih     = (const float*)d_in[4];
    const float* b_hh     = (const float*)d_in[5];
    const float* h0       = (const float*)d_in[6];
    float* out = (float*)d_out;

    const size_t usW  = (size_t)Hh * Hh;     // w_hh bf16
    const size_t usWx = (size_t)Hh * Ii;     // w_ih bf16
    const size_t usH  = (size_t)2 * Bb * Hh; // h ping-pong
    const size_t usX  = (size_t)Bb * Tt * Ii;// input bf16
    const size_t need_fused = (usW + usWx + usH + usX) * 2 + 1024 * 4 + 256;

    unsigned short* w_hh_bf = (unsigned short*)d_ws;
    unsigned short* w_ih_bf = w_hh_bf + usW;
    unsigned short* h_bf    = w_ih_bf + usWx;

    if (ws_size >= need_fused) {
        // ---------- FUSED path ----------
        unsigned short* x_bf  = h_bf + usH;
        unsigned int*   flags = (unsigned int*)(x_bf + usX);

        hipLaunchKernelGGL(init_flags, dim3(1), dim3(1024), 0, stream, flags);
        hipLaunchKernelGGL(cvt_kernel, dim3((Hh * Hh) / 1024), dim3(256), 0,
                           stream, w_hh, w_hh_bf);
        hipLaunchKernelGGL(cvt_kernel, dim3((Hh * Ii) / 1024), dim3(256), 0,
                           stream, w_ih, w_ih_bf);
        hipLaunchKernelGGL(cvt_kernel, dim3((Bb * Hh) / 1024), dim3(256), 0,
                           stream, h0, h_bf);
        hipLaunchKernelGGL(cvt_kernel, dim3((Bb * Tt * Ii) / 1024), dim3(256), 0,
                           stream, input, x_bf);

        void* args[] = {(void*)&w_hh_bf, (void*)&w_ih_bf, (void*)&x_bf,
                        (void*)&h_bf, (void*)&b_ih, (void*)&b_hh,
                        (void*)&internal, (void*)&out, (void*)&flags};
        hipLaunchCooperativeKernel((void*)rnn_persistent_fused, dim3(NBLK),
                                   dim3(512), args, 0, stream);
    } else {
        // ---------- FALLBACK = round-14 configuration ----------
        unsigned int* flags = (unsigned int*)(h_bf + usH);

        hipLaunchKernelGGL(init_flags, dim3(1), dim3(1024), 0, stream, flags);
        hipLaunchKernelGGL(cvt_kernel, dim3((Hh * Hh) / 1024), dim3(256), 0,
                           stream, w_hh, w_hh_bf);
        hipLaunchKernelGGL(cvt_kernel, dim3((Hh * Ii) / 1024), dim3(256), 0,
                           stream, w_ih, w_ih_bf);
        hipLaunchKernelGGL(cvt_kernel, dim3((Bb * Hh) / 1024), dim3(256), 0,
                           stream, h0, h_bf);

        dim3 g1(Hh / 128, (Bb * Tt) / 128);
        hipLaunchKernelGGL(xproj_kernel, g1, dim3(256), 0, stream,
                           input, w_ih_bf, b_ih, out);

        void* args[] = {(void*)&w_hh_bf, (void*)&h_bf, (void*)&b_hh,
                        (void*)&internal, (void*)&out, (void*)&flags};
        hipLaunchCooperativeKernel((void*)rnn_persistent_fb, dim3(NBLK),
                                   dim3(512), args, 0, stream);
    }
}